// Round 1
// baseline (18203.661 us; speedup 1.0000x reference)
//
#include <hip/hip_runtime.h>
#include <hip/hip_bf16.h>

typedef short bf16x8 __attribute__((ext_vector_type(8)));
typedef float f32x4 __attribute__((ext_vector_type(4)));
typedef unsigned short u16;

#define EPSBN 1e-3f

__device__ __forceinline__ u16 f2b(float f){
  unsigned u = __float_as_uint(f);
  return (u16)((u + 0x7fffu + ((u >> 16) & 1u)) >> 16);
}
__device__ __forceinline__ float b2f(u16 v){ return __uint_as_float(((unsigned)v) << 16); }
__device__ __forceinline__ float sigm(float x){ return 1.f/(1.f + __expf(-x)); }
__device__ __forceinline__ float tanhx(float x){ return 2.f/(1.f + __expf(-2.f*x)) - 1.f; }

// ---------------- prep kernels ----------------

__global__ void prep_sv(const float* __restrict__ g1, const float* __restrict__ be1,
                        const float* __restrict__ m1, const float* __restrict__ v1,
                        float* __restrict__ s, float* __restrict__ tv){
  int k = blockIdx.x*256 + threadIdx.x;
  if (k < 512){
    float sv = g1[k] * rsqrtf(v1[k] + EPSBN);
    s[k] = sv;
    tv[k] = be1[k] - m1[k]*sv;
  }
}

__global__ void prep_b2p(const float* __restrict__ W2, const float* __restrict__ b2,
                         const float* __restrict__ tv, float* __restrict__ out){
  int col = blockIdx.x*256 + threadIdx.x;   // 2048
  float acc = b2[col];
  for (int k=0;k<512;++k) acc += tv[k] * W2[(size_t)k*2048 + col];
  out[col] = acc;
}

// in: [512][2048] f32 (optionally row-scaled by scale[k]) -> out bf16 [2048 perm][512]
// out row for col = gate*512 + wg*16 + j  is  wg*64 + gate*16 + j
__global__ void transpose_pack(const float* __restrict__ in, const float* __restrict__ scale,
                               u16* __restrict__ out){
  __shared__ float tile[64][65];
  int k0 = blockIdx.x * 64;
  int c0 = blockIdx.y * 64;
  int t = threadIdx.x;
  int cc = t & 63, kk0 = (t >> 6) * 16;
  #pragma unroll
  for (int i=0;i<16;++i){
    float v = in[(size_t)(k0 + kk0 + i)*2048 + c0 + cc];
    if (scale) v *= scale[k0 + kk0 + i];
    tile[kk0 + i][cc] = v;
  }
  __syncthreads();
  int cc2 = t >> 2, kp = t & 3;
  int col = c0 + cc2;
  int row = ((col >> 4) & 31)*64 + ((col >> 9) << 4) + (col & 15);
  bf16x8 v0, v1;
  #pragma unroll
  for (int i=0;i<8;++i){
    v0[i] = (short)f2b(tile[kp*16 + i][cc2]);
    v1[i] = (short)f2b(tile[kp*16 + 8 + i][cc2]);
  }
  u16* dst = out + (size_t)row*512 + k0 + kp*16;
  *(bf16x8*)dst = v0;
  *(bf16x8*)(dst + 8) = v1;
}

// W1 [5][2048] -> [2048 perm rows][32] bf16 (K padded 5->32)
__global__ void pack_w1(const float* __restrict__ W1, u16* __restrict__ out){
  int r = blockIdx.x*256 + threadIdx.x;  // 0..2047
  int wg = r >> 6, gate = (r >> 4) & 3, j = r & 15;
  int col = gate*512 + wg*16 + j;
  #pragma unroll
  for (int k=0;k<32;++k)
    out[(size_t)r*32 + k] = (k < 5) ? f2b(W1[(size_t)k*2048 + col]) : (u16)0;
}

// x [64][512][5] f32 -> [64][512][32] bf16 zero-padded
__global__ void pack_x(const float* __restrict__ x, u16* __restrict__ out){
  int i = blockIdx.x*256 + threadIdx.x;   // exactly 64*512*32
  int k = i & 31;
  int bt = i >> 5;
  out[i] = (k < 5) ? f2b(x[(size_t)bt*5 + k]) : (u16)0;
}

// ---------------- LSTM scan ----------------
// Grid: 128 blocks = 4 groups (16 batch each) x 32 WGs (16 h-cols each), 256 thr.
// Wave w owns K-range [w*128, w*128+128) of the K=512 contractions (partials
// reduced via LDS). Weights resident in registers as MFMA A-fragments.
template<int PHASE>
__global__ void __launch_bounds__(256, 1) scan_k(
    const u16* __restrict__ Ure, const u16* __restrict__ Wre,
    const u16* __restrict__ Xin, const float* __restrict__ bias,
    u16* __restrict__ hbuf,          // [2][64][512] bf16
    u16* __restrict__ seqout,        // phase1: x1 seq, phase2: xs seq
    const u16* __restrict__ seqin2,  // phase2: x1 seq (residual)
    float* __restrict__ h3out,       // phase3
    unsigned* __restrict__ cnt)
{
  const int bid = blockIdx.x;
  const int g = bid & 3, wg = bid >> 2;
  const int tid = threadIdx.x;
  const int w = tid >> 6;
  const int l = tid & 63;
  const int lm = l & 15, lh = l >> 4;
  const int bg0 = g * 16;
  const int col0 = wg * 16;
  const int j_own = w*4 + lh, b_own = lm;

  // resident A-frags: U (recurrent), per gate q, K-subrange of this wave
  bf16x8 aU[4][4];
  #pragma unroll
  for (int q=0;q<4;++q){
    const u16* up = Ure + (size_t)((wg*4+q)*16 + lm)*512 + w*128 + lh*8;
    #pragma unroll
    for (int ks=0;ks<4;++ks) aU[q][ks] = *(const bf16x8*)(up + ks*32);
  }
  bf16x8 aW[4][4];
  bf16x8 aW1[4];
  if constexpr (PHASE == 1){
    #pragma unroll
    for (int q=0;q<4;++q)
      aW1[q] = *(const bf16x8*)(Wre + (size_t)((wg*4+q)*16 + lm)*32 + lh*8);
  } else {
    #pragma unroll
    for (int q=0;q<4;++q){
      const u16* wp = Wre + (size_t)((wg*4+q)*16 + lm)*512 + w*128 + lh*8;
      #pragma unroll
      for (int ks=0;ks<4;++ks) aW[q][ks] = *(const bf16x8*)(wp + ks*32);
    }
  }

  float bias_g[4];
  #pragma unroll
  for (int q=0;q<4;++q) bias_g[q] = bias[q*512 + col0 + j_own];

  float c_state = 0.f;

  __shared__ float zex[4][4][16][17];         // [gate][K-part][j][b]
  __shared__ __align__(16) u16 hsh[16][16];   // [b][j]
  __shared__ __align__(16) u16 xsh[16][16];

  unsigned* cq = cnt + g*16;

  for (int t=0; t<512; ++t){
    f32x4 acc[4] = {};

    // -------- input projection (known data, off the h critical path) --------
    if constexpr (PHASE == 1){
      if (w == 0){
        bf16x8 bx = *(const bf16x8*)(Xin + ((size_t)(bg0+lm)*512 + t)*32 + lh*8);
        #pragma unroll
        for (int q=0;q<4;++q)
          acc[q] = __builtin_amdgcn_mfma_f32_16x16x32_bf16(aW1[q], bx, acc[q], 0,0,0);
      }
    } else {
      const u16* xp = Xin + ((size_t)(bg0+lm)*512 + t)*512 + w*128 + lh*8;
      bf16x8 bx[4];
      #pragma unroll
      for (int ks=0;ks<4;++ks) bx[ks] = *(const bf16x8*)(xp + ks*32);
      #pragma unroll
      for (int ks=0;ks<4;++ks){
        #pragma unroll
        for (int q=0;q<4;++q)
          acc[q] = __builtin_amdgcn_mfma_f32_16x16x32_bf16(aW[q][ks], bx[ks], acc[q], 0,0,0);
      }
    }

    // -------- wait until all 32 WGs of this group published h_{t-1} --------
    if (tid == 0){
      const unsigned target = (unsigned)(32*t);
      while (__hip_atomic_load(cq, __ATOMIC_RELAXED, __HIP_MEMORY_SCOPE_AGENT) < target)
        __builtin_amdgcn_s_sleep(1);
    }
    __syncthreads();
    __threadfence();   // acquire: make peers' h stores visible

    float x1res = 0.f;
    if constexpr (PHASE == 2)
      x1res = b2f(seqin2[((size_t)(bg0+b_own)*512 + t)*512 + col0 + j_own]);

    // -------- recurrent h @ U --------
    {
      const u16* hp = hbuf + ((size_t)((t+1)&1)*64 + bg0 + lm)*512 + w*128 + lh*8;
      bf16x8 bh[4];
      #pragma unroll
      for (int ks=0;ks<4;++ks) bh[ks] = *(const bf16x8*)(hp + ks*32);
      #pragma unroll
      for (int ks=0;ks<4;++ks){
        #pragma unroll
        for (int q=0;q<4;++q)
          acc[q] = __builtin_amdgcn_mfma_f32_16x16x32_bf16(aU[q][ks], bh[ks], acc[q], 0,0,0);
      }
    }

    // -------- reduce K-partials across waves, gates, state update --------
    #pragma unroll
    for (int q=0;q<4;++q){
      #pragma unroll
      for (int r=0;r<4;++r)
        zex[q][w][lh*4 + r][lm] = acc[q][r];
    }
    __syncthreads();

    float zv[4];
    #pragma unroll
    for (int q=0;q<4;++q)
      zv[q] = zex[q][0][j_own][b_own] + zex[q][1][j_own][b_own]
            + zex[q][2][j_own][b_own] + zex[q][3][j_own][b_own] + bias_g[q];

    float iv = sigm(zv[0]), fv = sigm(zv[1]), gv = tanhx(zv[2]), ov = sigm(zv[3]);
    c_state = fv * c_state + iv * gv;
    float hv = ov * tanhx(c_state);

    hsh[b_own][j_own] = f2b(hv);
    if constexpr (PHASE == 2) xsh[b_own][j_own] = f2b(x1res + hv);
    if constexpr (PHASE == 3){
      if (t == 511) h3out[(size_t)(bg0+b_own)*512 + col0 + j_own] = hv;
    }
    __syncthreads();

    // -------- coalesced publish (wave 0 only -> ordered before release RMW) --------
    if (tid < 32){
      int row = tid >> 1, half = tid & 1;
      u16* dst = hbuf + ((size_t)(t&1)*64 + bg0 + row)*512 + col0 + half*8;
      *(bf16x8*)dst = *(const bf16x8*)(&hsh[row][half*8]);
    } else if (PHASE != 3 && tid < 64){
      int t2 = tid - 32;
      int row = t2 >> 1, half = t2 & 1;
      const u16* src = (PHASE == 1) ? &hsh[row][half*8] : &xsh[row][half*8];
      u16* dst = seqout + ((size_t)(bg0+row)*512 + t)*512 + col0 + half*8;
      *(bf16x8*)dst = *(const bf16x8*)src;
    }

    if (tid == 0)
      __hip_atomic_fetch_add(cq, 1u, __ATOMIC_RELEASE, __HIP_MEMORY_SCOPE_AGENT);
  }
}

// ---------------- dense heads ----------------
__global__ void __launch_bounds__(256) head_k(
    const float* __restrict__ h3,
    const float* __restrict__ d1w, const float* __restrict__ d1b,
    const float* __restrict__ g2, const float* __restrict__ be2,
    const float* __restrict__ m2, const float* __restrict__ v2,
    const float* __restrict__ d2w, const float* __restrict__ d2b,
    const float* __restrict__ hw, const float* __restrict__ hb,
    const float* __restrict__ d4w, const float* __restrict__ d4b,
    const float* __restrict__ d5w, const float* __restrict__ d5b,
    const float* __restrict__ rw, const float* __restrict__ rb,
    float* __restrict__ out)
{
  __shared__ float hl[512];
  __shared__ float a1[32], a2[16], c1[128], c2[64];
  int b = blockIdx.x, t = threadIdx.x;
  for (int i=t; i<512; i+=256) hl[i] = h3[(size_t)b*512 + i];
  __syncthreads();
  if (t < 32){
    float acc = d1b[t];
    for (int k=0;k<512;++k) acc += hl[k] * d1w[(size_t)k*32 + t];
    a1[t] = (acc - m2[t]) * (g2[t] * rsqrtf(v2[t] + EPSBN)) + be2[t];
  } else if (t >= 128){
    int i = t - 128;
    float acc = d4b[i];
    for (int k=0;k<512;++k) acc += hl[k] * d4w[(size_t)k*128 + i];
    c1[i] = acc;
  }
  __syncthreads();
  if (t < 16){
    float acc = d2b[t];
    for (int k=0;k<32;++k) acc += a1[k] * d2w[k*16 + t];
    a2[t] = acc;
  } else if (t >= 64 && t < 128){
    int i = t - 64;
    float acc = d5b[i];
    for (int k=0;k<128;++k) acc += c1[k] * d5w[k*64 + i];
    c2[i] = acc;
  }
  __syncthreads();
  if (t == 0){
    float acc = hb[0];
    for (int k=0;k<16;++k) acc += a2[k] * hw[k];
    out[b] = 1.f/(1.f + __expf(-acc));
  } else if (t >= 32 && t < 37){
    int i = t - 32;
    float acc = rb[i];
    for (int k=0;k<64;++k) acc += c2[k] * rw[k*5 + i];
    out[64 + b*5 + i] = acc;
  }
}

// ---------------- launch ----------------
extern "C" void kernel_launch(void* const* d_in, const int* in_sizes, int n_in,
                              void* d_out, int out_size, void* d_ws, size_t ws_size,
                              hipStream_t stream)
{
  const float* x   = (const float*)d_in[0];
  const float* W1  = (const float*)d_in[1];
  const float* U1  = (const float*)d_in[2];
  const float* b1  = (const float*)d_in[3];
  const float* g1  = (const float*)d_in[4];
  const float* be1 = (const float*)d_in[5];
  const float* m1  = (const float*)d_in[6];
  const float* v1  = (const float*)d_in[7];
  const float* W2  = (const float*)d_in[8];
  const float* U2  = (const float*)d_in[9];
  const float* b2  = (const float*)d_in[10];
  const float* W3  = (const float*)d_in[11];
  const float* U3  = (const float*)d_in[12];
  const float* b3  = (const float*)d_in[13];
  const float* d1w = (const float*)d_in[14];
  const float* d1b = (const float*)d_in[15];
  const float* g2  = (const float*)d_in[16];
  const float* be2 = (const float*)d_in[17];
  const float* m2  = (const float*)d_in[18];
  const float* v2  = (const float*)d_in[19];
  const float* d2w = (const float*)d_in[20];
  const float* d2b = (const float*)d_in[21];
  const float* hw  = (const float*)d_in[22];
  const float* hb  = (const float*)d_in[23];
  const float* d4w = (const float*)d_in[24];
  const float* d4b = (const float*)d_in[25];
  const float* d5w = (const float*)d_in[26];
  const float* d5b = (const float*)d_in[27];
  const float* rw  = (const float*)d_in[28];
  const float* rb  = (const float*)d_in[29];

  char* ws = (char*)d_ws;
  constexpr size_t SZ_W   = 2048ull*512*2;         // 2 MiB, packed weight
  constexpr size_t o_Ure1 = 0;
  constexpr size_t o_Ure2 = o_Ure1 + SZ_W;
  constexpr size_t o_Ure3 = o_Ure2 + SZ_W;
  constexpr size_t o_W2p  = o_Ure3 + SZ_W;
  constexpr size_t o_W3p  = o_W2p + SZ_W;
  constexpr size_t o_W1p  = o_W3p + SZ_W;          // 2048*32*2 = 128 KiB
  constexpr size_t o_xpad = o_W1p + 2048ull*32*2;  // 2 MiB
  constexpr size_t o_b2p  = o_xpad + 64ull*512*32*2;
  constexpr size_t o_s    = o_b2p + 2048ull*4;
  constexpr size_t o_tv   = o_s + 512ull*4;
  constexpr size_t o_h3   = o_tv + 512ull*4;
  constexpr size_t o_h    = o_h3 + 64ull*512*4;    // 3 phases x [2][64][512] bf16
  constexpr size_t SZ_H   = 3ull*2*64*512*2;       // 393216
  constexpr size_t o_cnt  = o_h + SZ_H;
  constexpr size_t SZ_CNT = 1024;
  constexpr size_t o_x1   = o_cnt + SZ_CNT;        // 32 MiB bf16 seq
  constexpr size_t o_xs   = o_x1 + 64ull*512*512*2;

  u16* Ure1 = (u16*)(ws + o_Ure1);
  u16* Ure2 = (u16*)(ws + o_Ure2);
  u16* Ure3 = (u16*)(ws + o_Ure3);
  u16* W2p  = (u16*)(ws + o_W2p);
  u16* W3p  = (u16*)(ws + o_W3p);
  u16* W1p  = (u16*)(ws + o_W1p);
  u16* xpad = (u16*)(ws + o_xpad);
  u16* x1p  = (u16*)(ws + o_x1);
  u16* xsp  = (u16*)(ws + o_xs);

  hipMemsetAsync(ws + o_h, 0, SZ_H + SZ_CNT, stream);

  prep_sv<<<dim3(2), dim3(256), 0, stream>>>(g1, be1, m1, v1, (float*)(ws+o_s), (float*)(ws+o_tv));
  transpose_pack<<<dim3(8,32), dim3(256), 0, stream>>>(U1, nullptr, Ure1);
  transpose_pack<<<dim3(8,32), dim3(256), 0, stream>>>(U2, nullptr, Ure2);
  transpose_pack<<<dim3(8,32), dim3(256), 0, stream>>>(U3, nullptr, Ure3);
  transpose_pack<<<dim3(8,32), dim3(256), 0, stream>>>(W3, nullptr, W3p);
  transpose_pack<<<dim3(8,32), dim3(256), 0, stream>>>(W2, (const float*)(ws+o_s), W2p);
  prep_b2p<<<dim3(8), dim3(256), 0, stream>>>(W2, b2, (const float*)(ws+o_tv), (float*)(ws+o_b2p));
  pack_w1<<<dim3(8), dim3(256), 0, stream>>>(W1, W1p);
  pack_x<<<dim3(4096), dim3(256), 0, stream>>>(x, xpad);

  scan_k<1><<<dim3(128), dim3(256), 0, stream>>>(Ure1, W1p, xpad, b1,
      (u16*)(ws+o_h), x1p, nullptr, nullptr, (unsigned*)(ws+o_cnt));
  scan_k<2><<<dim3(128), dim3(256), 0, stream>>>(Ure2, W2p, x1p, (const float*)(ws+o_b2p),
      (u16*)(ws+o_h+131072), xsp, x1p, nullptr, (unsigned*)(ws+o_cnt+256));
  scan_k<3><<<dim3(128), dim3(256), 0, stream>>>(Ure3, W3p, xsp, b3,
      (u16*)(ws+o_h+262144), nullptr, nullptr, (float*)(ws+o_h3), (unsigned*)(ws+o_cnt+512));

  head_k<<<dim3(64), dim3(256), 0, stream>>>((const float*)(ws+o_h3),
      d1w, d1b, g2, be2, m2, v2, d2w, d2b, hw, hb, d4w, d4b, d5w, d5b, rw, rb,
      (float*)d_out);
}

// Round 3
// 6149.995 us; speedup vs baseline: 2.9599x; 2.9599x over previous
//
#include <hip/hip_runtime.h>
#include <hip/hip_bf16.h>

typedef short bf16x8 __attribute__((ext_vector_type(8)));
typedef float f32x4 __attribute__((ext_vector_type(4)));
typedef unsigned short u16;
typedef unsigned int u32;
typedef unsigned long long u64;

#define EPSBN 1e-3f

__device__ __forceinline__ u16 f2b(float f){
  unsigned u = __float_as_uint(f);
  return (u16)((u + 0x7fffu + ((u >> 16) & 1u)) >> 16);
}
__device__ __forceinline__ float b2f(u16 v){ return __uint_as_float(((unsigned)v) << 16); }
__device__ __forceinline__ float sigm(float x){ return 1.f/(1.f + __expf(-x)); }
__device__ __forceinline__ float tanhx(float x){ return 2.f/(1.f + __expf(-2.f*x)) - 1.f; }

union U64x2 { u64 q[2]; bf16x8 v; };

// ---------------- prep kernels ----------------

__global__ void prep_sv(const float* __restrict__ g1, const float* __restrict__ be1,
                        const float* __restrict__ m1, const float* __restrict__ v1,
                        float* __restrict__ s, float* __restrict__ tv){
  int k = blockIdx.x*256 + threadIdx.x;
  if (k < 512){
    float sv = g1[k] * rsqrtf(v1[k] + EPSBN);
    s[k] = sv;
    tv[k] = be1[k] - m1[k]*sv;
  }
}

__global__ void prep_b2p(const float* __restrict__ W2, const float* __restrict__ b2,
                         const float* __restrict__ tv, float* __restrict__ out){
  int col = blockIdx.x*256 + threadIdx.x;   // 2048
  float acc = b2[col];
  for (int k=0;k<512;++k) acc += tv[k] * W2[(size_t)k*2048 + col];
  out[col] = acc;
}

// in: [512][2048] f32 (optionally row-scaled by scale[k]) -> out bf16 [2048 perm][512]
// col c = q*512 + hcol, hcol = wg*32 + jt*16 + jj  ->  row = wg*128 + q*32 + jt*16 + jj
__global__ void transpose_pack(const float* __restrict__ in, const float* __restrict__ scale,
                               u16* __restrict__ out){
  __shared__ float tile[64][65];
  int k0 = blockIdx.x * 64;
  int c0 = blockIdx.y * 64;
  int t = threadIdx.x;
  int cc = t & 63, kk0 = (t >> 6) * 16;
  #pragma unroll
  for (int i=0;i<16;++i){
    float v = in[(size_t)(k0 + kk0 + i)*2048 + c0 + cc];
    if (scale) v *= scale[k0 + kk0 + i];
    tile[kk0 + i][cc] = v;
  }
  __syncthreads();
  int cc2 = t >> 2, kp = t & 3;
  int col = c0 + cc2;
  int hcol = col & 511;
  int row = (hcol >> 5)*128 + (col >> 9)*32 + ((hcol >> 4) & 1)*16 + (col & 15);
  bf16x8 v0, v1;
  #pragma unroll
  for (int i=0;i<8;++i){
    v0[i] = (short)f2b(tile[kp*16 + i][cc2]);
    v1[i] = (short)f2b(tile[kp*16 + 8 + i][cc2]);
  }
  u16* dst = out + (size_t)row*512 + k0 + kp*16;
  *(bf16x8*)dst = v0;
  *(bf16x8*)(dst + 8) = v1;
}

// W1 [5][2048] -> [2048 perm rows][32] bf16 (K padded 5->32)
__global__ void pack_w1(const float* __restrict__ W1, u16* __restrict__ out){
  int r = blockIdx.x*256 + threadIdx.x;  // 0..2047
  int wg = r >> 7, q = (r >> 5) & 3, jt = (r >> 4) & 1, jj = r & 15;
  int col = q*512 + wg*32 + jt*16 + jj;
  #pragma unroll
  for (int k=0;k<32;++k)
    out[(size_t)r*32 + k] = (k < 5) ? f2b(W1[(size_t)k*2048 + col]) : (u16)0;
}

// x [64][512][5] f32 -> [64][512][32] bf16 zero-padded
__global__ void pack_x(const float* __restrict__ x, u16* __restrict__ out){
  int i = blockIdx.x*256 + threadIdx.x;   // exactly 64*512*32
  int k = i & 31;
  int bt = i >> 5;
  out[i] = (k < 5) ? f2b(x[(size_t)bt*5 + k]) : (u16)0;
}

// ---------------- LSTM scan ----------------
// Grid: 64 blocks = 4 groups (16 batch each) x 16 WGs (32 h-cols each), 256 thr.
// Wave w owns K-range [w*128, w*128+128). Weights (U and W) register-resident.
// Cross-WG h exchange: cache-bypassing atomic stores/loads (no fences), monotone
// counter per group (relaxed RMW after vmcnt-drained barrier).
template<int PHASE>
__global__ void __launch_bounds__(256, 1) scan_k(
    const u16* __restrict__ Ure, const u16* __restrict__ Wre,
    const u16* __restrict__ Xin, const float* __restrict__ bias,
    u32* __restrict__ hbuf32,        // [2][64][256] u32 (bf16 pairs)
    u32* __restrict__ seqout32,      // [64][512][256] u32
    const u16* __restrict__ seqin2,  // phase2: x1 seq (residual)
    float* __restrict__ h3out,       // phase3
    u32* __restrict__ cnt)
{
  const int bid = blockIdx.x;
  const int g = bid & 3, wg = bid >> 2;
  const int tid = threadIdx.x;
  const int w = tid >> 6, l = tid & 63;
  const int lm = l & 15, lh = l >> 4;
  const int bg0 = g * 16;
  const int b_own = tid & 15, jl = tid >> 4;   // thread owns (batch=b_own, cols jl, jl+16)
  const int pb = tid >> 4, pj = tid & 15;      // publish ownership: batch pb, u32 idx pj

  // resident A-frags: U (recurrent), 8 tiles (gate q, j-tile jt), 4 K-frags
  bf16x8 aU[8][4];
  #pragma unroll
  for (int q=0;q<4;++q)
    #pragma unroll
    for (int jt=0;jt<2;++jt){
      const u16* up = Ure + (size_t)(wg*128 + q*32 + jt*16 + lm)*512 + w*128 + lh*8;
      #pragma unroll
      for (int ks=0;ks<4;++ks) aU[q*2+jt][ks] = *(const bf16x8*)(up + ks*32);
    }
  bf16x8 aW[8][4];
  bf16x8 aW1[8];
  if constexpr (PHASE == 1){
    #pragma unroll
    for (int q=0;q<4;++q)
      #pragma unroll
      for (int jt=0;jt<2;++jt)
        aW1[q*2+jt] = *(const bf16x8*)(Wre + (size_t)(wg*128 + q*32 + jt*16 + lm)*32 + lh*8);
  } else {
    #pragma unroll
    for (int q=0;q<4;++q)
      #pragma unroll
      for (int jt=0;jt<2;++jt){
        const u16* wp = Wre + (size_t)(wg*128 + q*32 + jt*16 + lm)*512 + w*128 + lh*8;
        #pragma unroll
        for (int ks=0;ks<4;++ks) aW[q*2+jt][ks] = *(const bf16x8*)(wp + ks*32);
      }
  }

  float bias_g[4][2];
  #pragma unroll
  for (int q=0;q<4;++q){
    bias_g[q][0] = bias[q*512 + wg*32 + jl];
    bias_g[q][1] = bias[q*512 + wg*32 + jl + 16];
  }

  float cs0 = 0.f, cs1 = 0.f;

  __shared__ float zex[8][4][16][17];          // [tile][K-part][j(=D row m)][b(=D col n)]
  __shared__ __align__(8) u16 hsh[16][32];     // [b][hcol]
  __shared__ __align__(8) u16 xsh[16][32];

  u32* cq = cnt + g*32;
  const u64* hbase = (const u64*)hbuf32;

  for (int t=0; t<512; ++t){
    f32x4 acc[8] = {};

    // -------- input projection (known data, overlaps the wait) --------
    if constexpr (PHASE == 1){
      if (w == 0){
        bf16x8 bx = *(const bf16x8*)(Xin + ((size_t)(bg0+lm)*512 + t)*32 + lh*8);
        #pragma unroll
        for (int i=0;i<8;++i)
          acc[i] = __builtin_amdgcn_mfma_f32_16x16x32_bf16(aW1[i], bx, acc[i], 0,0,0);
      }
    } else {
      const u16* xp = Xin + ((size_t)(bg0+lm)*512 + t)*512 + w*128 + lh*8;
      bf16x8 bx[4];
      #pragma unroll
      for (int ks=0;ks<4;++ks) bx[ks] = *(const bf16x8*)(xp + ks*32);
      #pragma unroll
      for (int ks=0;ks<4;++ks){
        #pragma unroll
        for (int i=0;i<8;++i)
          acc[i] = __builtin_amdgcn_mfma_f32_16x16x32_bf16(aW[i][ks], bx[ks], acc[i], 0,0,0);
      }
    }

    float x1r0 = 0.f, x1r1 = 0.f;
    if constexpr (PHASE == 2){
      const u16* rp = seqin2 + ((size_t)(bg0+b_own)*512 + t)*512 + wg*32 + jl;
      x1r0 = b2f(rp[0]);
      x1r1 = b2f(rp[16]);
    }

    // -------- wait until all 16 WGs of this group published h_{t-1} --------
    if (tid == 0){
      const u32 target = (u32)(16*t);
      while (__hip_atomic_load(cq, __ATOMIC_RELAXED, __HIP_MEMORY_SCOPE_AGENT) < target) {}
    }
    __syncthreads();

    // -------- recurrent h @ U (cache-bypassing loads) --------
    {
      const u64* hp = hbase + (size_t)(((t+1)&1)*64 + bg0 + lm)*128 + w*32 + lh*2;
      U64x2 hq[4];
      #pragma unroll
      for (int ks=0;ks<4;++ks){
        hq[ks].q[0] = __hip_atomic_load(hp + ks*8,     __ATOMIC_RELAXED, __HIP_MEMORY_SCOPE_AGENT);
        hq[ks].q[1] = __hip_atomic_load(hp + ks*8 + 1, __ATOMIC_RELAXED, __HIP_MEMORY_SCOPE_AGENT);
      }
      #pragma unroll
      for (int ks=0;ks<4;++ks){
        #pragma unroll
        for (int i=0;i<8;++i)
          acc[i] = __builtin_amdgcn_mfma_f32_16x16x32_bf16(aU[i][ks], hq[ks].v, acc[i], 0,0,0);
      }
    }

    // -------- reduce K-partials across waves, gates, state update --------
    #pragma unroll
    for (int i=0;i<8;++i){
      #pragma unroll
      for (int r=0;r<4;++r)
        zex[i][w][lh*4 + r][lm] = acc[i][r];   // [j=m][b=n]
    }
    __syncthreads();

    float hv0, hv1;
    {
      float zv[4][2];
      #pragma unroll
      for (int q=0;q<4;++q){
        #pragma unroll
        for (int s2=0;s2<2;++s2)
          zv[q][s2] = zex[q*2+s2][0][jl][b_own] + zex[q*2+s2][1][jl][b_own]
                    + zex[q*2+s2][2][jl][b_own] + zex[q*2+s2][3][jl][b_own] + bias_g[q][s2];
      }
      float iv = sigm(zv[0][0]), fv = sigm(zv[1][0]), gv = tanhx(zv[2][0]), ov = sigm(zv[3][0]);
      cs0 = fv * cs0 + iv * gv;
      hv0 = ov * tanhx(cs0);
      iv = sigm(zv[0][1]); fv = sigm(zv[1][1]); gv = tanhx(zv[2][1]); ov = sigm(zv[3][1]);
      cs1 = fv * cs1 + iv * gv;
      hv1 = ov * tanhx(cs1);
    }

    hsh[b_own][jl]      = f2b(hv0);
    hsh[b_own][jl + 16] = f2b(hv1);
    if constexpr (PHASE == 2){
      xsh[b_own][jl]      = f2b(x1r0 + hv0);
      xsh[b_own][jl + 16] = f2b(x1r1 + hv1);
    }
    if constexpr (PHASE == 3){
      if (t == 511){
        h3out[(size_t)(bg0+b_own)*512 + wg*32 + jl]      = hv0;
        h3out[(size_t)(bg0+b_own)*512 + wg*32 + jl + 16] = hv1;
      }
    }
    __syncthreads();

    // -------- publish h (bypassing stores), drain, bump counter --------
    u32 pv = (u32)hsh[pb][2*pj] | ((u32)hsh[pb][2*pj+1] << 16);
    __hip_atomic_store(hbuf32 + (size_t)((t&1)*64 + bg0 + pb)*256 + wg*16 + pj, pv,
                       __ATOMIC_RELAXED, __HIP_MEMORY_SCOPE_AGENT);
    asm volatile("s_waitcnt vmcnt(0)" ::: "memory");
    __syncthreads();   // all WG stores drained before the counter bump
    if (tid == 0)
      __hip_atomic_fetch_add(cq, 1u, __ATOMIC_RELAXED, __HIP_MEMORY_SCOPE_AGENT);

    // -------- sequence output (off critical path) --------
    if constexpr (PHASE != 3){
      u32 sv;
      if constexpr (PHASE == 1) sv = pv;
      else sv = (u32)xsh[pb][2*pj] | ((u32)xsh[pb][2*pj+1] << 16);
      __builtin_nontemporal_store(sv, seqout32 + ((size_t)(bg0+pb)*512 + t)*256 + wg*16 + pj);
    }
  }
}

// ---------------- dense heads ----------------
__global__ void __launch_bounds__(256) head_k(
    const float* __restrict__ h3,
    const float* __restrict__ d1w, const float* __restrict__ d1b,
    const float* __restrict__ g2, const float* __restrict__ be2,
    const float* __restrict__ m2, const float* __restrict__ v2,
    const float* __restrict__ d2w, const float* __restrict__ d2b,
    const float* __restrict__ hw, const float* __restrict__ hb,
    const float* __restrict__ d4w, const float* __restrict__ d4b,
    const float* __restrict__ d5w, const float* __restrict__ d5b,
    const float* __restrict__ rw, const float* __restrict__ rb,
    float* __restrict__ out)
{
  __shared__ float hl[512];
  __shared__ float a1[32], a2[16], c1[128], c2[64];
  int b = blockIdx.x, t = threadIdx.x;
  for (int i=t; i<512; i+=256) hl[i] = h3[(size_t)b*512 + i];
  __syncthreads();
  if (t < 32){
    float acc = d1b[t];
    for (int k=0;k<512;++k) acc += hl[k] * d1w[(size_t)k*32 + t];
    a1[t] = (acc - m2[t]) * (g2[t] * rsqrtf(v2[t] + EPSBN)) + be2[t];
  } else if (t >= 128){
    int i = t - 128;
    float acc = d4b[i];
    for (int k=0;k<512;++k) acc += hl[k] * d4w[(size_t)k*128 + i];
    c1[i] = acc;
  }
  __syncthreads();
  if (t < 16){
    float acc = d2b[t];
    for (int k=0;k<32;++k) acc += a1[k] * d2w[k*16 + t];
    a2[t] = acc;
  } else if (t >= 64 && t < 128){
    int i = t - 64;
    float acc = d5b[i];
    for (int k=0;k<128;++k) acc += c1[k] * d5w[k*64 + i];
    c2[i] = acc;
  }
  __syncthreads();
  if (t == 0){
    float acc = hb[0];
    for (int k=0;k<16;++k) acc += a2[k] * hw[k];
    out[b] = 1.f/(1.f + __expf(-acc));
  } else if (t >= 32 && t < 37){
    int i = t - 32;
    float acc = rb[i];
    for (int k=0;k<64;++k) acc += c2[k] * rw[k*5 + i];
    out[64 + b*5 + i] = acc;
  }
}

// ---------------- launch ----------------
extern "C" void kernel_launch(void* const* d_in, const int* in_sizes, int n_in,
                              void* d_out, int out_size, void* d_ws, size_t ws_size,
                              hipStream_t stream)
{
  const float* x   = (const float*)d_in[0];
  const float* W1  = (const float*)d_in[1];
  const float* U1  = (const float*)d_in[2];
  const float* b1  = (const float*)d_in[3];
  const float* g1  = (const float*)d_in[4];
  const float* be1 = (const float*)d_in[5];
  const float* m1  = (const float*)d_in[6];
  const float* v1  = (const float*)d_in[7];
  const float* W2  = (const float*)d_in[8];
  const float* U2  = (const float*)d_in[9];
  const float* b2  = (const float*)d_in[10];
  const float* W3  = (const float*)d_in[11];
  const float* U3  = (const float*)d_in[12];
  const float* b3  = (const float*)d_in[13];
  const float* d1w = (const float*)d_in[14];
  const float* d1b = (const float*)d_in[15];
  const float* g2  = (const float*)d_in[16];
  const float* be2 = (const float*)d_in[17];
  const float* m2  = (const float*)d_in[18];
  const float* v2  = (const float*)d_in[19];
  const float* d2w = (const float*)d_in[20];
  const float* d2b = (const float*)d_in[21];
  const float* hw  = (const float*)d_in[22];
  const float* hb  = (const float*)d_in[23];
  const float* d4w = (const float*)d_in[24];
  const float* d4b = (const float*)d_in[25];
  const float* d5w = (const float*)d_in[26];
  const float* d5b = (const float*)d_in[27];
  const float* rw  = (const float*)d_in[28];
  const float* rb  = (const float*)d_in[29];

  char* ws = (char*)d_ws;
  constexpr size_t SZ_W   = 2048ull*512*2;         // 2 MiB per packed weight
  constexpr size_t o_Ure1 = 0;
  constexpr size_t o_Ure2 = o_Ure1 + SZ_W;
  constexpr size_t o_Ure3 = o_Ure2 + SZ_W;
  constexpr size_t o_W2p  = o_Ure3 + SZ_W;
  constexpr size_t o_W3p  = o_W2p + SZ_W;
  constexpr size_t o_W1p  = o_W3p + SZ_W;          // 128 KiB
  constexpr size_t o_xpad = o_W1p + 2048ull*32*2;  // 2 MiB
  constexpr size_t o_b2p  = o_xpad + 64ull*512*32*2;
  constexpr size_t o_s    = o_b2p + 2048ull*4;
  constexpr size_t o_tv   = o_s + 512ull*4;
  constexpr size_t o_h3   = o_tv + 512ull*4;
  constexpr size_t o_h    = o_h3 + 64ull*512*4;    // 3 phases x [2][64][256] u32
  constexpr size_t SZ_HP  = 2ull*64*256*4;         // 131072 per phase
  constexpr size_t SZ_H   = 3*SZ_HP;
  constexpr size_t o_cnt  = o_h + SZ_H;
  constexpr size_t SZ_CNT = 3*512;
  constexpr size_t o_x1   = o_cnt + 2048;          // 32 MiB bf16 seq
  constexpr size_t o_xs   = o_x1 + 64ull*512*512*2;

  u16* Ure1 = (u16*)(ws + o_Ure1);
  u16* Ure2 = (u16*)(ws + o_Ure2);
  u16* Ure3 = (u16*)(ws + o_Ure3);
  u16* W2p  = (u16*)(ws + o_W2p);
  u16* W3p  = (u16*)(ws + o_W3p);
  u16* W1p  = (u16*)(ws + o_W1p);
  u16* xpad = (u16*)(ws + o_xpad);
  u16* x1p  = (u16*)(ws + o_x1);
  u16* xsp  = (u16*)(ws + o_xs);

  hipMemsetAsync(ws + o_h, 0, SZ_H + SZ_CNT, stream);

  prep_sv<<<dim3(2), dim3(256), 0, stream>>>(g1, be1, m1, v1, (float*)(ws+o_s), (float*)(ws+o_tv));
  transpose_pack<<<dim3(8,32), dim3(256), 0, stream>>>(U1, nullptr, Ure1);
  transpose_pack<<<dim3(8,32), dim3(256), 0, stream>>>(U2, nullptr, Ure2);
  transpose_pack<<<dim3(8,32), dim3(256), 0, stream>>>(U3, nullptr, Ure3);
  transpose_pack<<<dim3(8,32), dim3(256), 0, stream>>>(W3, nullptr, W3p);
  transpose_pack<<<dim3(8,32), dim3(256), 0, stream>>>(W2, (const float*)(ws+o_s), W2p);
  prep_b2p<<<dim3(8), dim3(256), 0, stream>>>(W2, b2, (const float*)(ws+o_tv), (float*)(ws+o_b2p));
  pack_w1<<<dim3(8), dim3(256), 0, stream>>>(W1, W1p);
  pack_x<<<dim3(4096), dim3(256), 0, stream>>>(x, xpad);

  scan_k<1><<<dim3(64), dim3(256), 0, stream>>>(Ure1, W1p, xpad, b1,
      (u32*)(ws+o_h), (u32*)x1p, nullptr, nullptr, (u32*)(ws+o_cnt));
  scan_k<2><<<dim3(64), dim3(256), 0, stream>>>(Ure2, W2p, x1p, (const float*)(ws+o_b2p),
      (u32*)(ws+o_h+SZ_HP), (u32*)xsp, x1p, nullptr, (u32*)(ws+o_cnt+512));
  scan_k<3><<<dim3(64), dim3(256), 0, stream>>>(Ure3, W3p, xsp, b3,
      (u32*)(ws+o_h+2*SZ_HP), nullptr, nullptr, (float*)(ws+o_h3), (u32*)(ws+o_cnt+1024));

  head_k<<<dim3(64), dim3(256), 0, stream>>>((const float*)(ws+o_h3),
      d1w, d1b, g2, be2, m2, v2, d2w, d2b, hw, hb, d4w, d4b, d5w, d5b, rw, rb,
      (float*)d_out);
}

// Round 4
// 2337.504 us; speedup vs baseline: 7.7876x; 2.6310x over previous
//
#include <hip/hip_runtime.h>
#include <hip/hip_bf16.h>

typedef short bf16x8 __attribute__((ext_vector_type(8)));
typedef float f32x4 __attribute__((ext_vector_type(4)));
typedef unsigned short u16;
typedef unsigned int u32;
typedef unsigned long long u64;

#define EPSBN 1e-3f

__device__ __forceinline__ u16 f2b(float f){
  unsigned u = __float_as_uint(f);
  return (u16)((u + 0x7fffu + ((u >> 16) & 1u)) >> 16);
}
__device__ __forceinline__ float b2f(u16 v){ return __uint_as_float(((unsigned)v) << 16); }
__device__ __forceinline__ float sigm(float x){ return 1.f/(1.f + __expf(-x)); }
__device__ __forceinline__ float tanhx(float x){ return 2.f/(1.f + __expf(-2.f*x)) - 1.f; }

union U64x2 { u64 q[2]; bf16x8 v; };

// ---------------- prep kernels ----------------

__global__ void prep_sv(const float* __restrict__ g1, const float* __restrict__ be1,
                        const float* __restrict__ m1, const float* __restrict__ v1,
                        float* __restrict__ s, float* __restrict__ tv){
  int k = blockIdx.x*256 + threadIdx.x;
  if (k < 512){
    float sv = g1[k] * rsqrtf(v1[k] + EPSBN);
    s[k] = sv;
    tv[k] = be1[k] - m1[k]*sv;
  }
}

__global__ void prep_b2p(const float* __restrict__ W2, const float* __restrict__ b2,
                         const float* __restrict__ tv, float* __restrict__ out){
  int col = blockIdx.x*256 + threadIdx.x;   // 2048
  float acc = b2[col];
  for (int k=0;k<512;++k) acc += tv[k] * W2[(size_t)k*2048 + col];
  out[col] = acc;
}

// in: [512][2048] f32 (optionally row-scaled by scale[k]) -> out bf16 [2048 perm][512]
// col c = q*512 + hcol, hcol = wg*32 + jt*16 + jj  ->  row = wg*128 + q*32 + jt*16 + jj
__global__ void transpose_pack(const float* __restrict__ in, const float* __restrict__ scale,
                               u16* __restrict__ out){
  __shared__ float tile[64][65];
  int k0 = blockIdx.x * 64;
  int c0 = blockIdx.y * 64;
  int t = threadIdx.x;
  int cc = t & 63, kk0 = (t >> 6) * 16;
  #pragma unroll
  for (int i=0;i<16;++i){
    float v = in[(size_t)(k0 + kk0 + i)*2048 + c0 + cc];
    if (scale) v *= scale[k0 + kk0 + i];
    tile[kk0 + i][cc] = v;
  }
  __syncthreads();
  int cc2 = t >> 2, kp = t & 3;
  int col = c0 + cc2;
  int hcol = col & 511;
  int row = (hcol >> 5)*128 + (col >> 9)*32 + ((hcol >> 4) & 1)*16 + (col & 15);
  bf16x8 v0, v1;
  #pragma unroll
  for (int i=0;i<8;++i){
    v0[i] = (short)f2b(tile[kp*16 + i][cc2]);
    v1[i] = (short)f2b(tile[kp*16 + 8 + i][cc2]);
  }
  u16* dst = out + (size_t)row*512 + k0 + kp*16;
  *(bf16x8*)dst = v0;
  *(bf16x8*)(dst + 8) = v1;
}

// W1 [5][2048] -> [2048 perm rows][32] bf16 (K padded 5->32)
__global__ void pack_w1(const float* __restrict__ W1, u16* __restrict__ out){
  int r = blockIdx.x*256 + threadIdx.x;  // 0..2047
  int wg = r >> 7, q = (r >> 5) & 3, jt = (r >> 4) & 1, jj = r & 15;
  int col = q*512 + wg*32 + jt*16 + jj;
  #pragma unroll
  for (int k=0;k<32;++k)
    out[(size_t)r*32 + k] = (k < 5) ? f2b(W1[(size_t)k*2048 + col]) : (u16)0;
}

// x [64][512][5] f32 -> [64][512][32] bf16 zero-padded
__global__ void pack_x(const float* __restrict__ x, u16* __restrict__ out){
  int i = blockIdx.x*256 + threadIdx.x;   // exactly 64*512*32
  int k = i & 31;
  int bt = i >> 5;
  out[i] = (k < 5) ? f2b(x[(size_t)bt*5 + k]) : (u16)0;
}

// ---------------- fused pipelined 3-layer LSTM scan ----------------
// 192 blocks = 3 phases x (4 groups x 16 WGs), 256 thr. All co-resident.
// Phase p>0 at step t polls upstream seq-counter >= 16(t+1) (x[t] ready),
// then its own h-counter >= 16t. All cross-WG data moves via L3-bypassing
// atomic loads/stores; counters bumped after vmcnt(0)+barrier drain.
__global__ void __launch_bounds__(256, 1) scan_all(
    const u16* __restrict__ Ure1, const u16* __restrict__ Ure2, const u16* __restrict__ Ure3,
    const u16* __restrict__ W1p,  const u16* __restrict__ W2p,  const u16* __restrict__ W3p,
    const u16* __restrict__ xpad,
    const float* __restrict__ b1, const float* __restrict__ b2p, const float* __restrict__ b3,
    u32* __restrict__ hbuf_all,   // 3 x [2][64][256] u32
    u32* __restrict__ x1seq,      // [64][512][256] u32  (phase0 out = h1)
    u32* __restrict__ xsseq,      // [64][512][256] u32  (phase1 out = x1+h2)
    float* __restrict__ h3out, u32* __restrict__ cnt)
{
  const int bid = blockIdx.x;
  const int phase = bid >> 6;
  const int b6 = bid & 63;
  const int g = b6 & 3, wg = b6 >> 2;
  const int tid = threadIdx.x;
  const int w = tid >> 6, l = tid & 63;
  const int lm = l & 15, lh = l >> 4;
  const int bg0 = g * 16;
  const int b_own = tid & 15, jl = tid >> 4;   // thread owns (batch=b_own, cols jl, jl+16)
  const int pb = tid >> 4, pj = tid & 15;      // publish ownership: batch pb, u32 word pj

  const u16* Ure  = phase == 0 ? Ure1 : (phase == 1 ? Ure2 : Ure3);
  const u16* Wre  = phase == 0 ? W1p  : (phase == 1 ? W2p  : W3p);
  const float* bias = phase == 0 ? b1 : (phase == 1 ? b2p : b3);
  u32* hbuf32 = hbuf_all + (size_t)phase * 32768;           // 2*64*256
  u32* seqout = phase == 0 ? x1seq : (phase == 1 ? xsseq : nullptr);
  const u32* upseq = phase == 1 ? x1seq : (phase == 2 ? xsseq : nullptr);

  u32* cq  = cnt + (phase*4 + g)*64;       // own h-counter
  u32* sq_ = cq + 32;                      // own seq-counter
  u32* upq = (phase > 0) ? cnt + ((phase-1)*4 + g)*64 + 32 : nullptr;

  // resident A-frags: U (recurrent), 8 tiles (gate q, j-tile jt), 4 K-frags
  bf16x8 aU[8][4];
  #pragma unroll
  for (int q=0;q<4;++q)
    #pragma unroll
    for (int jt=0;jt<2;++jt){
      const u16* up = Ure + (size_t)(wg*128 + q*32 + jt*16 + lm)*512 + w*128 + lh*8;
      #pragma unroll
      for (int ks=0;ks<4;++ks) aU[q*2+jt][ks] = *(const bf16x8*)(up + ks*32);
    }
  bf16x8 aW[8][4];
  if (phase == 0){
    #pragma unroll
    for (int q=0;q<4;++q)
      #pragma unroll
      for (int jt=0;jt<2;++jt)
        aW[q*2+jt][0] = *(const bf16x8*)(Wre + (size_t)(wg*128 + q*32 + jt*16 + lm)*32 + lh*8);
  } else {
    #pragma unroll
    for (int q=0;q<4;++q)
      #pragma unroll
      for (int jt=0;jt<2;++jt){
        const u16* wp = Wre + (size_t)(wg*128 + q*32 + jt*16 + lm)*512 + w*128 + lh*8;
        #pragma unroll
        for (int ks=0;ks<4;++ks) aW[q*2+jt][ks] = *(const bf16x8*)(wp + ks*32);
      }
  }

  float bias_g[4][2];
  #pragma unroll
  for (int q=0;q<4;++q){
    bias_g[q][0] = bias[q*512 + wg*32 + jl];
    bias_g[q][1] = bias[q*512 + wg*32 + jl + 16];
  }

  float cs0 = 0.f, cs1 = 0.f;

  __shared__ float zex[8][4][16][17];          // [tile][K-part][j(=D row m)][b(=D col n)]
  __shared__ __align__(8) u16 hsh[16][32];     // [b][hcol]
  __shared__ __align__(8) u16 xsh[16][32];
  __shared__ u32 x1w[16][16];                  // phase1 residual words

  const u64* hbase = (const u64*)hbuf32;

  for (int t=0; t<512; ++t){
    f32x4 acc[8] = {};

    // -------- input projection --------
    if (phase == 0){
      if (w == 0){
        bf16x8 bx = *(const bf16x8*)(xpad + ((size_t)(bg0+lm)*512 + t)*32 + lh*8);
        #pragma unroll
        for (int i=0;i<8;++i)
          acc[i] = __builtin_amdgcn_mfma_f32_16x16x32_bf16(aW[i][0], bx, acc[i], 0,0,0);
      }
    } else {
      // wait for upstream x[t]
      if (tid == 0){
        const u32 target = (u32)(16*(t+1));
        while (__hip_atomic_load(upq, __ATOMIC_RELAXED, __HIP_MEMORY_SCOPE_AGENT) < target) {}
      }
      __syncthreads();
      if (phase == 1){   // residual x1 words for this WG's columns
        u32 rv = __hip_atomic_load(upseq + ((size_t)(bg0+pb)*512 + t)*256 + wg*16 + pj,
                                   __ATOMIC_RELAXED, __HIP_MEMORY_SCOPE_AGENT);
        x1w[pb][pj] = rv;
      }
      const u64* xp = (const u64*)upseq + ((size_t)(bg0+lm)*512 + t)*128 + w*32 + lh*2;
      U64x2 xq[4];
      #pragma unroll
      for (int ks=0;ks<4;++ks){
        xq[ks].q[0] = __hip_atomic_load(xp + ks*8,     __ATOMIC_RELAXED, __HIP_MEMORY_SCOPE_AGENT);
        xq[ks].q[1] = __hip_atomic_load(xp + ks*8 + 1, __ATOMIC_RELAXED, __HIP_MEMORY_SCOPE_AGENT);
      }
      #pragma unroll
      for (int ks=0;ks<4;++ks){
        #pragma unroll
        for (int i=0;i<8;++i)
          acc[i] = __builtin_amdgcn_mfma_f32_16x16x32_bf16(aW[i][ks], xq[ks].v, acc[i], 0,0,0);
      }
    }

    // -------- wait until all 16 WGs of this group published h_{t-1} --------
    if (tid == 0){
      const u32 target = (u32)(16*t);
      while (__hip_atomic_load(cq, __ATOMIC_RELAXED, __HIP_MEMORY_SCOPE_AGENT) < target) {}
    }
    __syncthreads();

    // -------- recurrent h @ U (bypassing loads) --------
    {
      const u64* hp = hbase + (size_t)(((t+1)&1)*64 + bg0 + lm)*128 + w*32 + lh*2;
      U64x2 hq[4];
      #pragma unroll
      for (int ks=0;ks<4;++ks){
        hq[ks].q[0] = __hip_atomic_load(hp + ks*8,     __ATOMIC_RELAXED, __HIP_MEMORY_SCOPE_AGENT);
        hq[ks].q[1] = __hip_atomic_load(hp + ks*8 + 1, __ATOMIC_RELAXED, __HIP_MEMORY_SCOPE_AGENT);
      }
      #pragma unroll
      for (int ks=0;ks<4;++ks){
        #pragma unroll
        for (int i=0;i<8;++i)
          acc[i] = __builtin_amdgcn_mfma_f32_16x16x32_bf16(aU[i][ks], hq[ks].v, acc[i], 0,0,0);
      }
    }

    // -------- reduce K-partials across waves, gates, state update --------
    #pragma unroll
    for (int i=0;i<8;++i){
      #pragma unroll
      for (int r=0;r<4;++r)
        zex[i][w][lh*4 + r][lm] = acc[i][r];   // [j=m][b=n]
    }
    __syncthreads();

    float hv0, hv1;
    {
      float zv[4][2];
      #pragma unroll
      for (int q=0;q<4;++q){
        #pragma unroll
        for (int s2=0;s2<2;++s2)
          zv[q][s2] = zex[q*2+s2][0][jl][b_own] + zex[q*2+s2][1][jl][b_own]
                    + zex[q*2+s2][2][jl][b_own] + zex[q*2+s2][3][jl][b_own] + bias_g[q][s2];
      }
      float iv = sigm(zv[0][0]), fv = sigm(zv[1][0]), gv = tanhx(zv[2][0]), ov = sigm(zv[3][0]);
      cs0 = fv * cs0 + iv * gv;
      hv0 = ov * tanhx(cs0);
      iv = sigm(zv[0][1]); fv = sigm(zv[1][1]); gv = tanhx(zv[2][1]); ov = sigm(zv[3][1]);
      cs1 = fv * cs1 + iv * gv;
      hv1 = ov * tanhx(cs1);
    }

    hsh[b_own][jl]      = f2b(hv0);
    hsh[b_own][jl + 16] = f2b(hv1);
    if (phase == 1){
      u32 w0 = x1w[b_own][jl >> 1], w1 = x1w[b_own][8 + (jl >> 1)];
      float x1r0 = b2f((u16)((jl & 1) ? (w0 >> 16) : (w0 & 0xffffu)));
      float x1r1 = b2f((u16)((jl & 1) ? (w1 >> 16) : (w1 & 0xffffu)));
      xsh[b_own][jl]      = f2b(x1r0 + hv0);
      xsh[b_own][jl + 16] = f2b(x1r1 + hv1);
    }
    if (phase == 2 && t == 511){
      h3out[(size_t)(bg0+b_own)*512 + wg*32 + jl]      = hv0;
      h3out[(size_t)(bg0+b_own)*512 + wg*32 + jl + 16] = hv1;
    }
    __syncthreads();

    // -------- publish h (+seq), drain, bump counters --------
    u32 pv = (u32)hsh[pb][2*pj] | ((u32)hsh[pb][2*pj+1] << 16);
    __hip_atomic_store(hbuf32 + (size_t)((t&1)*64 + bg0 + pb)*256 + wg*16 + pj, pv,
                       __ATOMIC_RELAXED, __HIP_MEMORY_SCOPE_AGENT);
    if (phase == 0){
      __hip_atomic_store(seqout + ((size_t)(bg0+pb)*512 + t)*256 + wg*16 + pj, pv,
                         __ATOMIC_RELAXED, __HIP_MEMORY_SCOPE_AGENT);
    } else if (phase == 1){
      u32 sv = (u32)xsh[pb][2*pj] | ((u32)xsh[pb][2*pj+1] << 16);
      __hip_atomic_store(seqout + ((size_t)(bg0+pb)*512 + t)*256 + wg*16 + pj, sv,
                         __ATOMIC_RELAXED, __HIP_MEMORY_SCOPE_AGENT);
    }
    asm volatile("s_waitcnt vmcnt(0)" ::: "memory");
    __syncthreads();   // all WG stores drained before counter bumps
    if (tid == 0){
      __hip_atomic_fetch_add(cq, 1u, __ATOMIC_RELAXED, __HIP_MEMORY_SCOPE_AGENT);
      if (phase < 2)
        __hip_atomic_fetch_add(sq_, 1u, __ATOMIC_RELAXED, __HIP_MEMORY_SCOPE_AGENT);
    }
  }
}

// ---------------- dense heads ----------------
__global__ void __launch_bounds__(256) head_k(
    const float* __restrict__ h3,
    const float* __restrict__ d1w, const float* __restrict__ d1b,
    const float* __restrict__ g2, const float* __restrict__ be2,
    const float* __restrict__ m2, const float* __restrict__ v2,
    const float* __restrict__ d2w, const float* __restrict__ d2b,
    const float* __restrict__ hw, const float* __restrict__ hb,
    const float* __restrict__ d4w, const float* __restrict__ d4b,
    const float* __restrict__ d5w, const float* __restrict__ d5b,
    const float* __restrict__ rw, const float* __restrict__ rb,
    float* __restrict__ out)
{
  __shared__ float hl[512];
  __shared__ float a1[32], a2[16], c1[128], c2[64];
  int b = blockIdx.x, t = threadIdx.x;
  for (int i=t; i<512; i+=256) hl[i] = h3[(size_t)b*512 + i];
  __syncthreads();
  if (t < 32){
    float acc = d1b[t];
    for (int k=0;k<512;++k) acc += hl[k] * d1w[(size_t)k*32 + t];
    a1[t] = (acc - m2[t]) * (g2[t] * rsqrtf(v2[t] + EPSBN)) + be2[t];
  } else if (t >= 128){
    int i = t - 128;
    float acc = d4b[i];
    for (int k=0;k<512;++k) acc += hl[k] * d4w[(size_t)k*128 + i];
    c1[i] = acc;
  }
  __syncthreads();
  if (t < 16){
    float acc = d2b[t];
    for (int k=0;k<32;++k) acc += a1[k] * d2w[k*16 + t];
    a2[t] = acc;
  } else if (t >= 64 && t < 128){
    int i = t - 64;
    float acc = d5b[i];
    for (int k=0;k<128;++k) acc += c1[k] * d5w[k*64 + i];
    c2[i] = acc;
  }
  __syncthreads();
  if (t == 0){
    float acc = hb[0];
    for (int k=0;k<16;++k) acc += a2[k] * hw[k];
    out[b] = 1.f/(1.f + __expf(-acc));
  } else if (t >= 32 && t < 37){
    int i = t - 32;
    float acc = rb[i];
    for (int k=0;k<64;++k) acc += c2[k] * rw[k*5 + i];
    out[64 + b*5 + i] = acc;
  }
}

// ---------------- launch ----------------
extern "C" void kernel_launch(void* const* d_in, const int* in_sizes, int n_in,
                              void* d_out, int out_size, void* d_ws, size_t ws_size,
                              hipStream_t stream)
{
  const float* x   = (const float*)d_in[0];
  const float* W1  = (const float*)d_in[1];
  const float* U1  = (const float*)d_in[2];
  const float* b1  = (const float*)d_in[3];
  const float* g1  = (const float*)d_in[4];
  const float* be1 = (const float*)d_in[5];
  const float* m1  = (const float*)d_in[6];
  const float* v1  = (const float*)d_in[7];
  const float* W2  = (const float*)d_in[8];
  const float* U2  = (const float*)d_in[9];
  const float* b2  = (const float*)d_in[10];
  const float* W3  = (const float*)d_in[11];
  const float* U3  = (const float*)d_in[12];
  const float* b3  = (const float*)d_in[13];
  const float* d1w = (const float*)d_in[14];
  const float* d1b = (const float*)d_in[15];
  const float* g2  = (const float*)d_in[16];
  const float* be2 = (const float*)d_in[17];
  const float* m2  = (const float*)d_in[18];
  const float* v2  = (const float*)d_in[19];
  const float* d2w = (const float*)d_in[20];
  const float* d2b = (const float*)d_in[21];
  const float* hw  = (const float*)d_in[22];
  const float* hb  = (const float*)d_in[23];
  const float* d4w = (const float*)d_in[24];
  const float* d4b = (const float*)d_in[25];
  const float* d5w = (const float*)d_in[26];
  const float* d5b = (const float*)d_in[27];
  const float* rw  = (const float*)d_in[28];
  const float* rb  = (const float*)d_in[29];

  char* ws = (char*)d_ws;
  constexpr size_t SZ_W   = 2048ull*512*2;         // 2 MiB per packed weight
  constexpr size_t o_Ure1 = 0;
  constexpr size_t o_Ure2 = o_Ure1 + SZ_W;
  constexpr size_t o_Ure3 = o_Ure2 + SZ_W;
  constexpr size_t o_W2p  = o_Ure3 + SZ_W;
  constexpr size_t o_W3p  = o_W2p + SZ_W;
  constexpr size_t o_W1p  = o_W3p + SZ_W;          // 128 KiB
  constexpr size_t o_xpad = o_W1p + 2048ull*32*2;  // 2 MiB
  constexpr size_t o_b2p  = o_xpad + 64ull*512*32*2;
  constexpr size_t o_s    = o_b2p + 2048ull*4;
  constexpr size_t o_tv   = o_s + 512ull*4;
  constexpr size_t o_h3   = o_tv + 512ull*4;
  constexpr size_t o_h    = o_h3 + 64ull*512*4;    // 3 phases x [2][64][256] u32
  constexpr size_t SZ_HP  = 2ull*64*256*4;         // 131072 per phase
  constexpr size_t SZ_H   = 3*SZ_HP;
  constexpr size_t o_cnt  = o_h + SZ_H;
  constexpr size_t SZ_CNT = 3ull*4*64*4;           // 3 phases x 4 groups x 64 u32
  constexpr size_t o_x1   = o_cnt + 4096;          // 32 MiB u32-seq
  constexpr size_t o_xs   = o_x1 + 64ull*512*512*2;

  u16* Ure1 = (u16*)(ws + o_Ure1);
  u16* Ure2 = (u16*)(ws + o_Ure2);
  u16* Ure3 = (u16*)(ws + o_Ure3);
  u16* W2p  = (u16*)(ws + o_W2p);
  u16* W3p  = (u16*)(ws + o_W3p);
  u16* W1p  = (u16*)(ws + o_W1p);
  u16* xpad = (u16*)(ws + o_xpad);
  u32* x1p  = (u32*)(ws + o_x1);
  u32* xsp  = (u32*)(ws + o_xs);

  hipMemsetAsync(ws + o_h, 0, SZ_H + SZ_CNT, stream);

  prep_sv<<<dim3(2), dim3(256), 0, stream>>>(g1, be1, m1, v1, (float*)(ws+o_s), (float*)(ws+o_tv));
  transpose_pack<<<dim3(8,32), dim3(256), 0, stream>>>(U1, nullptr, Ure1);
  transpose_pack<<<dim3(8,32), dim3(256), 0, stream>>>(U2, nullptr, Ure2);
  transpose_pack<<<dim3(8,32), dim3(256), 0, stream>>>(U3, nullptr, Ure3);
  transpose_pack<<<dim3(8,32), dim3(256), 0, stream>>>(W3, nullptr, W3p);
  transpose_pack<<<dim3(8,32), dim3(256), 0, stream>>>(W2, (const float*)(ws+o_s), W2p);
  prep_b2p<<<dim3(8), dim3(256), 0, stream>>>(W2, b2, (const float*)(ws+o_tv), (float*)(ws+o_b2p));
  pack_w1<<<dim3(8), dim3(256), 0, stream>>>(W1, W1p);
  pack_x<<<dim3(4096), dim3(256), 0, stream>>>(x, xpad);

  scan_all<<<dim3(192), dim3(256), 0, stream>>>(
      Ure1, Ure2, Ure3, W1p, W2p, W3p, xpad,
      b1, (const float*)(ws+o_b2p), b3,
      (u32*)(ws+o_h), x1p, xsp,
      (float*)(ws+o_h3), (u32*)(ws+o_cnt));

  head_k<<<dim3(64), dim3(256), 0, stream>>>((const float*)(ws+o_h3),
      d1w, d1b, g2, be2, m2, v2, d2w, d2b, hw, hb, d4w, d4b, d5w, d5b, rw, rb,
      (float*)d_out);
}